// Round 2
// baseline (2006.739 us; speedup 1.0000x reference)
//
#include <hip/hip_runtime.h>

#define L_DIM 2048
#define C_DIM 512
#define B_DIM 8

// bf16 <-> f32 via bit patterns (RNE rounding on pack)
__device__ __forceinline__ float bf2f(ushort u) {
  union { float f; unsigned int i; } c; c.i = ((unsigned int)u) << 16; return c.f;
}
__device__ __forceinline__ ushort f2bf(float f) {
  union { float f; unsigned int i; } c; c.f = f;
  unsigned int lsb = (c.i >> 16) & 1u;
  return (ushort)((c.i + 0x7FFFu + lsb) >> 16);
}

__device__ __forceinline__ float wave_red_max(float v) {
  #pragma unroll
  for (int o = 1; o < 64; o <<= 1) v = fmaxf(v, __shfl_xor(v, o, 64));
  return v;
}
__device__ __forceinline__ float wave_red_sum(float v) {
  #pragma unroll
  for (int o = 1; o < 64; o <<= 1) v += __shfl_xor(v, o, 64);
  return v;
}

// ---------------------------------------------------------------------------
// Generic 64x64-tile GEMM, BK=16, 256 threads, 4x4 microtile, fp32 accumulate.
// MODE 0: A = x fp32 [b][c][l] (fused transpose), B = W fp32 [n][K], +bias
//         -> out bf16 (q/k/v1/v2)
// MODE 1: A,B bf16 [m][K] row-major, *scale -> out bf16 (attn)
// MODE 2: A = exp(attn_bf16[m][k]-stm[m])/sts[m], B = v bf16 [k][n] -> fp32 vk
// MODE 3: A = exp(attn_bf16[k][m]-stm[m])/sts[m] (transposed),      -> fp32 vq
// ---------------------------------------------------------------------------
template <int MODE>
__global__ __launch_bounds__(256) void gemm64(
    const void* __restrict__ Av, const void* __restrict__ Bv,
    const float* __restrict__ bias, const float* __restrict__ stm,
    const float* __restrict__ sts, void* __restrict__ outv,
    const int K, const int ldo, const float scale,
    const size_t sA, const size_t sB, const size_t sO)
{
  __shared__ float As[16][68];
  __shared__ float Bs[16][68];
  __shared__ float smx[64], sinv[64];

  const int t  = threadIdx.x;
  const int m0 = blockIdx.x * 64, n0 = blockIdx.y * 64, z = blockIdx.z;

  if (MODE >= 2) {
    if (t < 64) {
      const int gm = z * L_DIM + m0 + t;
      smx[t]  = stm[gm];
      sinv[t] = 1.0f / sts[gm];
    }
    __syncthreads();
  }

  float acc[4][4] = {{0.f}};
  const int tx = t & 15, ty = t >> 4;

  for (int k0 = 0; k0 < K; k0 += 16) {
    // ---- stage A tile (16 k x 64 m) ----
    if (MODE == 0) {
      const float* Ab = (const float*)Av;         // x: [B][C][L] fp32
      const int i = t & 63, kg = t >> 6;
      const int b = m0 >> 11;                     // 64 | L -> tile within one batch
      const int l = (m0 & (L_DIM - 1)) + i;
      #pragma unroll
      for (int r = 0; r < 4; ++r) {
        const int c = k0 + kg * 4 + r;
        As[kg * 4 + r][i] = Ab[((size_t)b * C_DIM + c) * L_DIM + l];  // coalesced in l
      }
    } else if (MODE == 1 || MODE == 2) {
      const ushort* Ab = (const ushort*)Av + (size_t)z * sA;
      const int kc = t & 15;
      #pragma unroll
      for (int r = 0; r < 4; ++r) {
        const int i = (t >> 4) + 16 * r;
        float v = bf2f(Ab[(size_t)(m0 + i) * K + k0 + kc]);   // ldA == K
        if (MODE == 2) v = __expf(v - smx[i]) * sinv[i];
        As[kc][i] = v;
      }
    } else {  // MODE 3: transposed attn read, coalesced in m
      const ushort* Ab = (const ushort*)Av + (size_t)z * sA;
      const int i = t & 63, kg = t >> 6;
      #pragma unroll
      for (int r = 0; r < 4; ++r) {
        const int kc = kg * 4 + r;
        const float v = bf2f(Ab[(size_t)(k0 + kc) * L_DIM + m0 + i]);
        As[kc][i] = __expf(v - smx[i]) * sinv[i];
      }
    }
    // ---- stage B tile (16 k x 64 n) ----
    if (MODE == 0) {        // W fp32 [n][K], K-contiguous
      const float* Bb = (const float*)Bv;
      const int kc = t & 15;
      #pragma unroll
      for (int r = 0; r < 4; ++r) {
        const int j = (t >> 4) + 16 * r;
        Bs[kc][j] = Bb[(size_t)(n0 + j) * K + k0 + kc];
      }
    } else if (MODE == 1) { // k bf16 [n][K], K-contiguous
      const ushort* Bb = (const ushort*)Bv + (size_t)z * sB;
      const int kc = t & 15;
      #pragma unroll
      for (int r = 0; r < 4; ++r) {
        const int j = (t >> 4) + 16 * r;
        Bs[kc][j] = bf2f(Bb[(size_t)(n0 + j) * K + k0 + kc]);
      }
    } else {                // v bf16 [k][C], n-contiguous
      const ushort* Bb = (const ushort*)Bv + (size_t)z * sB;
      const int j = t & 63, kg = t >> 6;
      #pragma unroll
      for (int r = 0; r < 4; ++r) {
        const int kc = kg * 4 + r;
        Bs[kc][j] = bf2f(Bb[(size_t)(k0 + kc) * C_DIM + n0 + j]);
      }
    }
    __syncthreads();
    // ---- 4x4 microtile FMAs ----
    #pragma unroll
    for (int kc = 0; kc < 16; ++kc) {
      float av[4], bv[4];
      *(float4*)av = *(const float4*)&As[kc][ty * 4];
      *(float4*)bv = *(const float4*)&Bs[kc][tx * 4];
      #pragma unroll
      for (int u = 0; u < 4; ++u)
        #pragma unroll
        for (int v = 0; v < 4; ++v)
          acc[u][v] = fmaf(av[u], bv[v], acc[u][v]);
    }
    __syncthreads();
  }

  // ---- epilogue ----
  if (MODE <= 1) {
    ushort* ob = (ushort*)outv + (size_t)z * sO;
    #pragma unroll
    for (int u = 0; u < 4; ++u) {
      const int row = m0 + ty * 4 + u;
      ushort4 o;
      float v0 = acc[u][0] * scale, v1 = acc[u][1] * scale;
      float v2 = acc[u][2] * scale, v3 = acc[u][3] * scale;
      if (MODE == 0) {
        v0 += bias[n0 + tx * 4 + 0]; v1 += bias[n0 + tx * 4 + 1];
        v2 += bias[n0 + tx * 4 + 2]; v3 += bias[n0 + tx * 4 + 3];
      }
      o.x = f2bf(v0); o.y = f2bf(v1); o.z = f2bf(v2); o.w = f2bf(v3);
      *(ushort4*)&ob[(size_t)row * ldo + n0 + tx * 4] = o;
    }
  } else {
    float* ob = (float*)outv + (size_t)z * sO;
    #pragma unroll
    for (int u = 0; u < 4; ++u) {
      const int row = m0 + ty * 4 + u;
      float4 o = make_float4(acc[u][0], acc[u][1], acc[u][2], acc[u][3]);
      *(float4*)&ob[(size_t)row * ldo + n0 + tx * 4] = o;
    }
  }
}

// ---------------------------------------------------------------------------
// Row softmax stats over bf16 attn: max + sum(exp) per (b, qi) row.
// ---------------------------------------------------------------------------
__global__ __launch_bounds__(256) void row_stats(const ushort* __restrict__ attn,
    float* __restrict__ rmax, float* __restrict__ rsum)
{
  __shared__ float buf[L_DIM];
  __shared__ float red[8];
  const int b = blockIdx.y, qi = blockIdx.x, t = threadIdx.x;
  const ushort* row = attn + ((size_t)b * L_DIM + qi) * L_DIM;
  float m = -1e30f;
  for (int i = t; i < L_DIM; i += 256) { float v = bf2f(row[i]); buf[i] = v; m = fmaxf(m, v); }
  m = wave_red_max(m);
  if ((t & 63) == 0) red[t >> 6] = m;
  __syncthreads();
  m = fmaxf(fmaxf(red[0], red[1]), fmaxf(red[2], red[3]));
  float s = 0.f;
  for (int i = t; i < L_DIM; i += 256) s += __expf(buf[i] - m);
  s = wave_red_sum(s);
  if ((t & 63) == 0) red[4 + (t >> 6)] = s;
  __syncthreads();
  if (t == 0) {
    rmax[(size_t)b * L_DIM + qi] = m;
    rsum[(size_t)b * L_DIM + qi] = red[4] + red[5] + red[6] + red[7];
  }
}

// ---------------------------------------------------------------------------
// Column softmax stats, online single pass, split 16-ways over q.
// ---------------------------------------------------------------------------
__global__ __launch_bounds__(256) void col_part(const ushort* __restrict__ attn,
    float* __restrict__ pm, float* __restrict__ ps)
{
  const int b  = blockIdx.y;
  const int kj = blockIdx.x * 256 + threadIdx.x;
  const int q0 = blockIdx.z * (L_DIM / 16);
  const ushort* base = attn + (size_t)b * L_DIM * L_DIM + kj;
  float m = -1e30f, s = 0.f;
  for (int q = q0; q < q0 + L_DIM / 16; ++q) {
    float v = bf2f(base[(size_t)q * L_DIM]);
    if (v > m) { s = fmaf(s, __expf(m - v), 1.f); m = v; }
    else       { s += __expf(v - m); }
  }
  const size_t o = ((size_t)blockIdx.z * B_DIM + b) * L_DIM + kj;
  pm[o] = m; ps[o] = s;
}

__global__ __launch_bounds__(256) void col_combine(const float* __restrict__ pm,
    const float* __restrict__ ps, float* __restrict__ cm, float* __restrict__ cs)
{
  const int i = blockIdx.x * 256 + threadIdx.x;  // 0 .. B*L-1
  const int n = B_DIM * L_DIM;
  float m = -1e30f;
  #pragma unroll
  for (int p = 0; p < 16; ++p) m = fmaxf(m, pm[(size_t)p * n + i]);
  float s = 0.f;
  #pragma unroll
  for (int p = 0; p < 16; ++p) s += ps[(size_t)p * n + i] * __expf(pm[(size_t)p * n + i] - m);
  cm[i] = m; cs[i] = s;
}

// ---------------------------------------------------------------------------
// LayerNorm over C + cross skip + transpose back to (B, C, L).
// ---------------------------------------------------------------------------
__global__ __launch_bounds__(256) void ln_out(const float* __restrict__ vx,
    const float* __restrict__ xo, const float* __restrict__ gamma,
    const float* __restrict__ beta, float* __restrict__ out)
{
  __shared__ float s[16][513];
  __shared__ float mu[16], rsd[16];
  __shared__ float gb[512], bb[512];
  const int t = threadIdx.x;
  const int b = blockIdx.y, l0 = blockIdx.x * 16;
  #pragma unroll
  for (int r = 0; r < 2; ++r) { gb[r * 256 + t] = gamma[r * 256 + t]; bb[r * 256 + t] = beta[r * 256 + t]; }
  const float* vb = vx + ((size_t)b * L_DIM + l0) * C_DIM;
  for (int it = 0; it < 32; ++it) {
    const int idx = it * 256 + t, l = idx >> 9, c = idx & 511;
    s[l][c] = vb[(size_t)l * C_DIM + c];                 // coalesced in c
  }
  __syncthreads();
  const float* xb = xo + (size_t)b * C_DIM * L_DIM + l0;
  for (int it = 0; it < 32; ++it) {
    const int idx = it * 256 + t, c = idx >> 4, l = idx & 15;
    s[l][c] += xb[(size_t)c * L_DIM + l];                // coalesced in l
  }
  __syncthreads();
  const int w = t >> 6, lane = t & 63;
  #pragma unroll
  for (int rr = 0; rr < 4; ++rr) {
    const int l = w * 4 + rr;
    float sum = 0.f, sq = 0.f;
    #pragma unroll
    for (int c0 = 0; c0 < 512; c0 += 64) {
      const float v = s[l][c0 + lane];
      sum += v; sq = fmaf(v, v, sq);
    }
    sum = wave_red_sum(sum); sq = wave_red_sum(sq);
    if (lane == 0) {
      const float m = sum * (1.f / 512.f);
      const float var = sq * (1.f / 512.f) - m * m;
      mu[l] = m; rsd[l] = rsqrtf(var + 1e-5f);
    }
  }
  __syncthreads();
  float* ob = out + (size_t)b * C_DIM * L_DIM + l0;
  for (int it = 0; it < 32; ++it) {
    const int idx = it * 256 + t, c = idx >> 4, l = idx & 15;
    const float v = (s[l][c] - mu[l]) * rsd[l] * gb[c] + bb[c];
    ob[(size_t)c * L_DIM + l] = v;                       // coalesced in l
  }
}

// ---------------------------------------------------------------------------
extern "C" void kernel_launch(void* const* d_in, const int* in_sizes, int n_in,
                              void* d_out, int out_size, void* d_ws, size_t ws_size,
                              hipStream_t stream) {
  const float* x1   = (const float*)d_in[0];
  const float* x2   = (const float*)d_in[1];
  const float* w_q  = (const float*)d_in[2];
  const float* b_q  = (const float*)d_in[3];
  const float* w_k  = (const float*)d_in[4];
  const float* b_k  = (const float*)d_in[5];
  const float* w_v1 = (const float*)d_in[6];
  const float* b_v1 = (const float*)d_in[7];
  const float* w_v2 = (const float*)d_in[8];
  const float* b_v2 = (const float*)d_in[9];
  const float* gamma= (const float*)d_in[10];
  const float* beta = (const float*)d_in[11];
  float* out = (float*)d_out;

  const size_t MC = (size_t)B_DIM * L_DIM * C_DIM;   // 8,388,608
  const size_t LL = (size_t)B_DIM * L_DIM * L_DIM;   // 33,554,432
  const size_t BL = (size_t)B_DIM * L_DIM;           // 16,384

  // ---- workspace: exactly 128 MiB of bf16 intermediates ----
  ushort* q    = (ushort*)d_ws;        // 16 MiB
  ushort* kbuf = q + MC;               // 16 MiB
  ushort* v1   = kbuf + MC;            // 16 MiB
  ushort* v2   = v1 + MC;              // 16 MiB
  ushort* attn = v2 + MC;              // 64 MiB
  // fp32 vq/vk alias the dead q+k region (32 MiB = MC floats)
  float* vtmp = (float*)d_ws;

  // ---- softmax stats live at the front of d_out (consumed before ln_out) ----
  float* rmax = out;            // BL
  float* rsum = out + BL;       // BL
  float* cmax = out + 2 * BL;   // BL
  float* csum = out + 3 * BL;   // BL
  float* pm   = out + 4 * BL;   // 16*BL
  float* ps   = out + 20 * BL;  // 16*BL   (total 36*BL = 589,824 floats << MC)

  const float iscale = 0.044194173824159216f;  // 1/sqrt(512)
  const dim3 blk(256);
  const size_t sQ = (size_t)L_DIM * C_DIM;
  const size_t sAT = (size_t)L_DIM * L_DIM;

  // projections (fused transpose of x), bf16 outputs
  gemm64<0><<<dim3(256, 8, 1), blk, 0, stream>>>(x1, w_q,  b_q,  nullptr, nullptr, q,    C_DIM, C_DIM, 1.0f, 0, 0, 0);
  gemm64<0><<<dim3(256, 8, 1), blk, 0, stream>>>(x2, w_k,  b_k,  nullptr, nullptr, kbuf, C_DIM, C_DIM, 1.0f, 0, 0, 0);
  gemm64<0><<<dim3(256, 8, 1), blk, 0, stream>>>(x1, w_v1, b_v1, nullptr, nullptr, v1,   C_DIM, C_DIM, 1.0f, 0, 0, 0);
  gemm64<0><<<dim3(256, 8, 1), blk, 0, stream>>>(x2, w_v2, b_v2, nullptr, nullptr, v2,   C_DIM, C_DIM, 1.0f, 0, 0, 0);
  // attn = q @ k^T / sqrt(C), bf16
  gemm64<1><<<dim3(32, 32, 8), blk, 0, stream>>>(q, kbuf, nullptr, nullptr, nullptr, attn, C_DIM, L_DIM, iscale, sQ, sQ, sAT);
  // softmax stats (stored in d_out scratch region)
  row_stats<<<dim3(L_DIM, B_DIM), blk, 0, stream>>>(attn, rmax, rsum);
  col_part<<<dim3(L_DIM / 256, B_DIM, 16), blk, 0, stream>>>(attn, pm, ps);
  col_combine<<<dim3(BL / 256), blk, 0, stream>>>(pm, ps, cmax, csum);
  // vq = colsoftmax(attn)^T @ v1 (fp32, into dead q+k region), then its LN
  gemm64<3><<<dim3(32, 8, 8), blk, 0, stream>>>(attn, v1, nullptr, cmax, csum, vtmp, L_DIM, C_DIM, 1.0f, sAT, sQ, sQ);
  ln_out<<<dim3(L_DIM / 16, B_DIM), blk, 0, stream>>>(vtmp, x2, gamma, beta, out + MC);
  // vk = rowsoftmax(attn) @ v2 (reuses same region), then its LN
  gemm64<2><<<dim3(32, 8, 8), blk, 0, stream>>>(attn, v2, nullptr, rmax, rsum, vtmp, L_DIM, C_DIM, 1.0f, sAT, sQ, sQ);
  ln_out<<<dim3(L_DIM / 16, B_DIM), blk, 0, stream>>>(vtmp, x1, gamma, beta, out);
}

// Round 3
// 378.127 us; speedup vs baseline: 5.3070x; 5.3070x over previous
//
#include <hip/hip_runtime.h>

#define L_DIM 2048
#define C_DIM 512
#define B_DIM 8

typedef __attribute__((ext_vector_type(8))) short bf16x8;   // 8 bf16 = 4 VGPR
typedef __attribute__((ext_vector_type(4))) float f32x4;    // MFMA acc

__device__ __forceinline__ float bf2f(ushort u) {
  union { float f; unsigned int i; } c; c.i = ((unsigned int)u) << 16; return c.f;
}
__device__ __forceinline__ ushort f2bf(float f) {
  union { float f; unsigned int i; } c; c.f = f;
  unsigned int lsb = (c.i >> 16) & 1u;
  return (ushort)((c.i + 0x7FFFu + lsb) >> 16);
}

__device__ __forceinline__ float wave_red_max(float v) {
  #pragma unroll
  for (int o = 1; o < 64; o <<= 1) v = fmaxf(v, __shfl_xor(v, o, 64));
  return v;
}
__device__ __forceinline__ float wave_red_sum(float v) {
  #pragma unroll
  for (int o = 1; o < 64; o <<= 1) v += __shfl_xor(v, o, 64);
  return v;
}

// ---------------------------------------------------------------------------
// Uniform bf16 MFMA GEMM. Tile 128x128, BK=64, 256 thr = 4 waves (2x2).
// A: [m][K] bf16 row-major (lda), B: [n][K] bf16 row-major (ldb). D = A.B^T.
// SOFT=1: A-elements become exp(a - stm[m]) at staging; acc *= 1/sts[m] at epi.
// EPI: 0 = row-major store (outN, ldo), 1 = transposed store (outT, ldoT),
//      2 = both. All stores bf16, via swizzled LDS bounce (coalesced).
// LDS tiles swizzled: elem(r, kk) = r*64 + 8*((kk>>3) ^ (r&7)) + (kk&7).
// ---------------------------------------------------------------------------
template <int SOFT, int EPI, bool BIAS>
__global__ __launch_bounds__(256) void gemm_mfma(
    const ushort* __restrict__ A, const ushort* __restrict__ B,
    const float* __restrict__ bias, const float* __restrict__ stm,
    const float* __restrict__ sts,
    ushort* __restrict__ outN, ushort* __restrict__ outT,
    const int K, const int lda, const int ldb, const int ldo, const int ldoT,
    const float scale,
    const size_t szA, const size_t szB, const size_t szO, const size_t szOT)
{
  __shared__ __align__(16) ushort lds[16384];   // As 8192 | Bs 8192 ; Cs reuses all
  ushort* As = lds;
  ushort* Bs = lds + 8192;
  __shared__ float pst[128], pinv[128];

  const int t = threadIdx.x;
  const int lane = t & 63, w = t >> 6;
  const int wr = w >> 1, wc = w & 1;
  const int l16 = lane & 15, lhi = lane >> 4;
  const int m0 = blockIdx.x * 128, n0 = blockIdx.y * 128, z = blockIdx.z;

  const ushort* Ab = A + (size_t)z * szA;
  const ushort* Bb = B + (size_t)z * szB;

  if (SOFT) {
    if (t < 128) {
      const int gm = z * L_DIM + m0 + t;
      pst[t]  = stm[gm];
      pinv[t] = 1.0f / sts[gm];
    }
  }

  f32x4 acc[4][4];
  #pragma unroll
  for (int i = 0; i < 4; ++i)
    #pragma unroll
    for (int j = 0; j < 4; ++j) { f32x4 zv = {0.f, 0.f, 0.f, 0.f}; acc[i][j] = zv; }

  bf16x8 rA[4], rB[4];
  auto loadRegs = [&](int k0) {
    #pragma unroll
    for (int p = 0; p < 4; ++p) {
      const int id = p * 256 + t, r = id >> 3, sl = id & 7;
      rA[p] = *(const bf16x8*)(Ab + (size_t)(m0 + r) * lda + k0 + sl * 8);
      rB[p] = *(const bf16x8*)(Bb + (size_t)(n0 + r) * ldb + k0 + sl * 8);
    }
  };
  auto writeLDS = [&]() {
    #pragma unroll
    for (int p = 0; p < 4; ++p) {
      const int id = p * 256 + t, r = id >> 3, sl = id & 7;
      bf16x8 va = rA[p];
      if (SOFT) {
        const float mx = pst[r];
        bf16x8 tv;
        #pragma unroll
        for (int j = 0; j < 8; ++j)
          tv[j] = (short)f2bf(__expf(bf2f((ushort)va[j]) - mx));
        va = tv;
      }
      *(bf16x8*)&As[r * 64 + 8 * (sl ^ (r & 7))] = va;
      *(bf16x8*)&Bs[r * 64 + 8 * (sl ^ (r & 7))] = rB[p];
    }
  };

  const int KT = K >> 6;
  loadRegs(0);
  for (int kt = 0; kt < KT; ++kt) {
    __syncthreads();               // LDS free (also orders pst on iter 0)
    writeLDS();
    __syncthreads();
    if (kt + 1 < KT) loadRegs((kt + 1) << 6);   // prefetch next tile (T14)
    #pragma unroll
    for (int ks = 0; ks < 2; ++ks) {
      bf16x8 af[4], bg[4];
      #pragma unroll
      for (int i = 0; i < 4; ++i) {
        const int ra = wr * 64 + i * 16 + l16;
        af[i] = *(const bf16x8*)&As[ra * 64 + 8 * ((ks * 4 + lhi) ^ (ra & 7))];
        const int rb = wc * 64 + i * 16 + l16;
        bg[i] = *(const bf16x8*)&Bs[rb * 64 + 8 * ((ks * 4 + lhi) ^ (rb & 7))];
      }
      #pragma unroll
      for (int i = 0; i < 4; ++i)
        #pragma unroll
        for (int j = 0; j < 4; ++j)
          acc[i][j] = __builtin_amdgcn_mfma_f32_16x16x32_bf16(af[i], bg[j], acc[i][j], 0, 0, 0);
    }
  }

  // ---- epilogue: bounce C tile (128x128 bf16) through swizzled LDS ----
  // Cs elem(r, c) = r*128 + 8*((c>>3) ^ (r&15)) + (c&7)
  __syncthreads();
  ushort* Cs = lds;
  #pragma unroll
  for (int i = 0; i < 4; ++i) {
    #pragma unroll
    for (int j = 0; j < 4; ++j) {
      const int er = wr * 64 + i * 16 + lhi * 4;       // C/D: row=(lane>>4)*4+reg
      const int ec = wc * 64 + j * 16 + l16;           //      col=lane&15
      const float bv = BIAS ? bias[n0 + ec] : 0.f;
      #pragma unroll
      for (int r = 0; r < 4; ++r) {
        float val = acc[i][j][r] * scale;
        if (SOFT) val *= pinv[er + r];
        if (BIAS) val += bv;
        const int rr = er + r;
        Cs[rr * 128 + 8 * ((ec >> 3) ^ (rr & 15)) + (ec & 7)] = f2bf(val);
      }
    }
  }
  __syncthreads();
  if (EPI == 0 || EPI == 2) {
    ushort* ob = outN + (size_t)z * szO;
    #pragma unroll
    for (int p = 0; p < 8; ++p) {
      const int id = p * 256 + t, r = id >> 4, sl = id & 15;
      bf16x8 v = *(const bf16x8*)&Cs[r * 128 + 8 * (sl ^ (r & 15))];
      *(bf16x8*)(ob + (size_t)(m0 + r) * ldo + n0 + sl * 8) = v;
    }
  }
  if (EPI == 1 || EPI == 2) {
    ushort* obT = outT + (size_t)z * szOT;
    #pragma unroll
    for (int p = 0; p < 8; ++p) {
      const int id = p * 256 + t, c = id >> 4, rs = id & 15;
      bf16x8 tv;
      #pragma unroll
      for (int jj = 0; jj < 8; ++jj) {
        const int rr = rs * 8 + jj;
        tv[jj] = (short)Cs[rr * 128 + 8 * ((c >> 3) ^ (rr & 15)) + (c & 7)];
      }
      *(bf16x8*)(obT + (size_t)(n0 + c) * ldoT + m0 + rs * 8) = tv;
    }
  }
}

// ---------------------------------------------------------------------------
// Row softmax stats over a bf16 [rows][2048] matrix: per-row max & sum(exp).
// ---------------------------------------------------------------------------
__global__ __launch_bounds__(256) void row_stats(const ushort* __restrict__ attn,
    float* __restrict__ rmax, float* __restrict__ rsum)
{
  __shared__ float red[8];
  const int b = blockIdx.y, qi = blockIdx.x, t = threadIdx.x;
  const ushort* row = attn + ((size_t)b * L_DIM + qi) * L_DIM;
  bf16x8 v = *(const bf16x8*)&row[t * 8];
  float f[8];
  #pragma unroll
  for (int j = 0; j < 8; ++j) f[j] = bf2f((ushort)v[j]);
  float m = f[0];
  #pragma unroll
  for (int j = 1; j < 8; ++j) m = fmaxf(m, f[j]);
  m = wave_red_max(m);
  if ((t & 63) == 0) red[t >> 6] = m;
  __syncthreads();
  m = fmaxf(fmaxf(red[0], red[1]), fmaxf(red[2], red[3]));
  float s = 0.f;
  #pragma unroll
  for (int j = 0; j < 8; ++j) s += __expf(f[j] - m);
  s = wave_red_sum(s);
  if ((t & 63) == 0) red[4 + (t >> 6)] = s;
  __syncthreads();
  if (t == 0) {
    rmax[(size_t)b * L_DIM + qi] = m;
    rsum[(size_t)b * L_DIM + qi] = red[4] + red[5] + red[6] + red[7];
  }
}

// ---------------------------------------------------------------------------
// x [B][C][L] fp32 -> xT [B][L][C] bf16 (64x64 LDS tile transpose)
// ---------------------------------------------------------------------------
__global__ __launch_bounds__(256) void xpose(const float* __restrict__ x,
                                             ushort* __restrict__ xT)
{
  __shared__ float s[64][65];
  const int b = blockIdx.z, l0 = blockIdx.x * 64, c0 = blockIdx.y * 64;
  const int t = threadIdx.x;
  const float* xb = x + ((size_t)b * C_DIM + c0) * L_DIM + l0;
  #pragma unroll
  for (int p = 0; p < 16; ++p) {
    const int c = p * 4 + (t >> 6);
    s[c][t & 63] = xb[(size_t)c * L_DIM + (t & 63)];
  }
  __syncthreads();
  ushort* ob = xT + ((size_t)b * L_DIM + l0) * C_DIM + c0;
  #pragma unroll
  for (int p = 0; p < 16; ++p) {
    const int l = p * 4 + (t >> 6);
    ob[(size_t)l * C_DIM + (t & 63)] = f2bf(s[t & 63][l]);
  }
}

__global__ __launch_bounds__(256) void cvtw(const float* __restrict__ w,
                                            ushort* __restrict__ o)
{
  const int i = blockIdx.x * 256 + threadIdx.x;
  o[i] = f2bf(w[i]);
}

// ---------------------------------------------------------------------------
// LayerNorm over C + cross skip + transpose back to (B, C, L). vx is bf16.
// ---------------------------------------------------------------------------
__global__ __launch_bounds__(256) void ln_out(const ushort* __restrict__ vx,
    const float* __restrict__ xo, const float* __restrict__ gamma,
    const float* __restrict__ beta, float* __restrict__ out)
{
  __shared__ float s[16][513];
  __shared__ float mu[16], rsd[16];
  __shared__ float gb[512], bb[512];
  const int t = threadIdx.x;
  const int b = blockIdx.y, l0 = blockIdx.x * 16;
  #pragma unroll
  for (int r = 0; r < 2; ++r) { gb[r * 256 + t] = gamma[r * 256 + t]; bb[r * 256 + t] = beta[r * 256 + t]; }
  const ushort* vb = vx + ((size_t)b * L_DIM + l0) * C_DIM;
  #pragma unroll
  for (int p = 0; p < 4; ++p) {
    const int id = p * 256 + t;                 // 1024 chunks of 8 bf16
    const int l = id >> 6, cb = (id & 63) * 8;
    bf16x8 v = *(const bf16x8*)&vb[(size_t)l * C_DIM + cb];
    #pragma unroll
    for (int j = 0; j < 8; ++j) s[l][cb + j] = bf2f((ushort)v[j]);
  }
  __syncthreads();
  const float* xb = xo + (size_t)b * C_DIM * L_DIM + l0;
  for (int it = 0; it < 32; ++it) {
    const int idx = it * 256 + t, c = idx >> 4, l = idx & 15;
    s[l][c] += xb[(size_t)c * L_DIM + l];       // coalesced in l
  }
  __syncthreads();
  const int w = t >> 6, lane = t & 63;
  #pragma unroll
  for (int rr = 0; rr < 4; ++rr) {
    const int l = w * 4 + rr;
    float sum = 0.f, sq = 0.f;
    #pragma unroll
    for (int c0 = 0; c0 < 512; c0 += 64) {
      const float v = s[l][c0 + lane];
      sum += v; sq = fmaf(v, v, sq);
    }
    sum = wave_red_sum(sum); sq = wave_red_sum(sq);
    if (lane == 0) {
      const float m = sum * (1.f / 512.f);
      const float var = sq * (1.f / 512.f) - m * m;
      mu[l] = m; rsd[l] = rsqrtf(var + 1e-5f);
    }
  }
  __syncthreads();
  float* ob = out + (size_t)b * C_DIM * L_DIM + l0;
  for (int it = 0; it < 32; ++it) {
    const int idx = it * 256 + t, c = idx >> 4, l = idx & 15;
    const float v = (s[l][c] - mu[l]) * rsd[l] * gb[c] + bb[c];
    ob[(size_t)c * L_DIM + l] = v;              // coalesced in l
  }
}

// ---------------------------------------------------------------------------
extern "C" void kernel_launch(void* const* d_in, const int* in_sizes, int n_in,
                              void* d_out, int out_size, void* d_ws, size_t ws_size,
                              hipStream_t stream) {
  const float* x1   = (const float*)d_in[0];
  const float* x2   = (const float*)d_in[1];
  const float* w_q  = (const float*)d_in[2];
  const float* b_q  = (const float*)d_in[3];
  const float* w_k  = (const float*)d_in[4];
  const float* b_k  = (const float*)d_in[5];
  const float* w_v1 = (const float*)d_in[6];
  const float* b_v1 = (const float*)d_in[7];
  const float* w_v2 = (const float*)d_in[8];
  const float* b_v2 = (const float*)d_in[9];
  const float* gamma= (const float*)d_in[10];
  const float* beta = (const float*)d_in[11];
  float* out = (float*)d_out;

  const size_t MC  = (size_t)B_DIM * L_DIM * C_DIM;   // 8,388,608
  const size_t LL  = (size_t)B_DIM * L_DIM * L_DIM;   // 33,554,432
  const size_t BL  = (size_t)B_DIM * L_DIM;           // 16,384
  const size_t sQ  = (size_t)L_DIM * C_DIM;           // per-batch q/k/v stride
  const size_t sAT = (size_t)L_DIM * L_DIM;           // per-batch attn stride

  // ---- ws: exactly 128 MiB bf16 ----
  ushort* q    = (ushort*)d_ws;        // 16 MiB
  ushort* kbuf = q + MC;               // 16 MiB
  ushort* v1T  = kbuf + MC;            // 16 MiB  [C][L] per batch
  ushort* v2T  = v1T + MC;             // 16 MiB
  ushort* attn = v2T + MC;             // 64 MiB  [q][k] per batch
  // overlays in the not-yet-written attn region (dead before QK^T):
  ushort* x1T = attn;                  // 16 MiB  [B][L][C]
  ushort* x2T = attn + MC;             // 16 MiB
  ushort* wbf = attn + 2 * MC;         // 4 x 256K = 2 MiB (q|k|v1|v2)
  // overlays in dead q (after QK^T): softmax stats
  float* rmax = (float*)q;             // BL floats each
  float* rsum = rmax + BL;
  float* cmax = rsum + BL;
  float* csum = cmax + BL;
  // PV results (bf16 [B][L][C]) in dead regions:
  ushort* vkbuf = kbuf;                // dead after QK^T
  ushort* vqbuf = v2T;                 // dead after vk GEMM
  // attnT [k][q] bf16 lives in d_out (64 MiB), dead before ln writes:
  ushort* attnT = (ushort*)d_out;

  const float iscale = 0.044194173824159216f;  // 1/sqrt(512)
  const dim3 blk(256);

  // 1) weights fp32 -> bf16
  cvtw<<<1024, blk, 0, stream>>>(w_q,  wbf);
  cvtw<<<1024, blk, 0, stream>>>(w_k,  wbf + 262144);
  cvtw<<<1024, blk, 0, stream>>>(w_v1, wbf + 524288);
  cvtw<<<1024, blk, 0, stream>>>(w_v2, wbf + 786432);
  // 2) x -> xT bf16
  xpose<<<dim3(32, 8, 8), blk, 0, stream>>>(x1, x1T);
  xpose<<<dim3(32, 8, 8), blk, 0, stream>>>(x2, x2T);
  // 3) projections: q,k row-major; v1,v2 transposed ([C][L])
  gemm_mfma<0,0,true><<<dim3(16,4,8), blk, 0, stream>>>(x1T, wbf,          b_q,  nullptr, nullptr, q,    nullptr, C_DIM, C_DIM, C_DIM, C_DIM, 0,     1.0f, sQ, 0, sQ, 0);
  gemm_mfma<0,0,true><<<dim3(16,4,8), blk, 0, stream>>>(x2T, wbf + 262144, b_k,  nullptr, nullptr, kbuf, nullptr, C_DIM, C_DIM, C_DIM, C_DIM, 0,     1.0f, sQ, 0, sQ, 0);
  gemm_mfma<0,1,true><<<dim3(16,4,8), blk, 0, stream>>>(x1T, wbf + 524288, b_v1, nullptr, nullptr, nullptr, v1T,  C_DIM, C_DIM, C_DIM, 0,     L_DIM, 1.0f, sQ, 0, 0, sQ);
  gemm_mfma<0,1,true><<<dim3(16,4,8), blk, 0, stream>>>(x2T, wbf + 786432, b_v2, nullptr, nullptr, nullptr, v2T,  C_DIM, C_DIM, C_DIM, 0,     L_DIM, 1.0f, sQ, 0, 0, sQ);
  // 4) attn = q.k^T * iscale -> attn AND attnT
  gemm_mfma<0,2,false><<<dim3(16,16,8), blk, 0, stream>>>(q, kbuf, nullptr, nullptr, nullptr, attn, attnT, C_DIM, C_DIM, C_DIM, L_DIM, L_DIM, iscale, sQ, sQ, sAT, sAT);
  // 5) softmax stats: rows of attn (softmax over k), rows of attnT (softmax over q)
  row_stats<<<dim3(L_DIM, B_DIM), blk, 0, stream>>>(attn,  rmax, rsum);
  row_stats<<<dim3(L_DIM, B_DIM), blk, 0, stream>>>(attnT, cmax, csum);
  // 6) vk = softmax_rows(attn) @ v2 ; vq = softmax_rows(attnT) @ v1
  gemm_mfma<1,0,false><<<dim3(16,4,8), blk, 0, stream>>>(attn,  v2T, nullptr, rmax, rsum, vkbuf, nullptr, L_DIM, L_DIM, L_DIM, C_DIM, 0, 1.0f, sAT, sQ, sQ, 0);
  gemm_mfma<1,0,false><<<dim3(16,4,8), blk, 0, stream>>>(attnT, v1T, nullptr, cmax, csum, vqbuf, nullptr, L_DIM, L_DIM, L_DIM, C_DIM, 0, 1.0f, sAT, sQ, sQ, 0);
  // 7) LN + skip + transpose back (clobbers attnT region of d_out -- now dead)
  ln_out<<<dim3(L_DIM / 16, B_DIM), blk, 0, stream>>>(vkbuf, x1, gamma, beta, out);
  ln_out<<<dim3(L_DIM / 16, B_DIM), blk, 0, stream>>>(vqbuf, x2, gamma, beta, out + MC);
}

// Round 4
// 371.559 us; speedup vs baseline: 5.4009x; 1.0177x over previous
//
#include <hip/hip_runtime.h>

#define L_DIM 2048
#define C_DIM 512
#define B_DIM 8

typedef __attribute__((ext_vector_type(8))) short bf16x8;   // 8 bf16 = 4 VGPR
typedef __attribute__((ext_vector_type(4))) float f32x4;    // MFMA acc

__device__ __forceinline__ float bf2f(ushort u) {
  union { float f; unsigned int i; } c; c.i = ((unsigned int)u) << 16; return c.f;
}
__device__ __forceinline__ ushort f2bf(float f) {
  union { float f; unsigned int i; } c; c.f = f;
  unsigned int lsb = (c.i >> 16) & 1u;
  return (ushort)((c.i + 0x7FFFu + lsb) >> 16);
}

__device__ __forceinline__ float wave_red_max(float v) {
  #pragma unroll
  for (int o = 1; o < 64; o <<= 1) v = fmaxf(v, __shfl_xor(v, o, 64));
  return v;
}
__device__ __forceinline__ float wave_red_sum(float v) {
  #pragma unroll
  for (int o = 1; o < 64; o <<= 1) v += __shfl_xor(v, o, 64);
  return v;
}

// async global->LDS, 16B per lane (dest = wave-uniform base + lane*16)
__device__ __forceinline__ void glds16(const ushort* g, ushort* l) {
  __builtin_amdgcn_global_load_lds(
      (const __attribute__((address_space(1))) void*)g,
      (__attribute__((address_space(3))) void*)l, 16, 0, 0);
}

// ---------------------------------------------------------------------------
// bf16 MFMA GEMM, D = A.B^T. Tile 128x128, BK=64, 256 thr = 4 waves (2x2).
// A: [m][K] bf16 (lda), B: [n][K] bf16 (ldb), both staged via global_load_lds
// with pre-swizzled global source: LDS[row][slot s] holds k-chunk s^(row&7).
// EPI: 0 = row-major store, 1 = transposed store, 2 = both (bf16, LDS bounce).
// ---------------------------------------------------------------------------
template <int EPI, bool BIAS>
__global__ __launch_bounds__(256) void gemm_mfma(
    const ushort* __restrict__ A, const ushort* __restrict__ B,
    const float* __restrict__ bias,
    ushort* __restrict__ outN, ushort* __restrict__ outT,
    const int K, const int lda, const int ldb, const int ldo, const int ldoT,
    const float scale,
    const size_t szA, const size_t szB, const size_t szO, const size_t szOT)
{
  __shared__ __align__(16) ushort lds[16384];   // As 8K | Bs 8K ; Cs reuses all
  ushort* As = lds;
  ushort* Bs = lds + 8192;

  const int t = threadIdx.x;
  const int lane = t & 63, w = t >> 6;
  const int wr = w >> 1, wc = w & 1;
  const int l16 = lane & 15, lhi = lane >> 4;
  const int m0 = blockIdx.x * 128, n0 = blockIdx.y * 128, z = blockIdx.z;

  const ushort* Ab = A + (size_t)z * szA;
  const ushort* Bb = B + (size_t)z * szB;

  f32x4 acc[4][4];
  #pragma unroll
  for (int i = 0; i < 4; ++i)
    #pragma unroll
    for (int j = 0; j < 4; ++j) { f32x4 zv = {0.f, 0.f, 0.f, 0.f}; acc[i][j] = zv; }

  // staging geometry: wave w, call p covers rows w*32+p*8 .. +7 of the tile;
  // lane l -> row +(l>>3), fetches global k-chunk ((l&7) ^ (row&7)) so that
  // LDS (linear dest) ends up swizzled: LDS[row][slot] = chunk slot^(row&7).
  const int lrow = lane >> 3;
  const int lsl  = lane & 7;

  const int KT = K >> 6;
  for (int kt = 0; kt < KT; ++kt) {
    const int k0 = kt << 6;
    __syncthreads();                      // previous tile's consumers done
    #pragma unroll
    for (int p = 0; p < 4; ++p) {
      const int rr = w * 32 + p * 8 + lrow;
      const int ch = lsl ^ (rr & 7);
      glds16(Ab + (size_t)(m0 + rr) * lda + k0 + ch * 8, As + (w * 32 + p * 8) * 64);
      glds16(Bb + (size_t)(n0 + rr) * ldb + k0 + ch * 8, Bs + (w * 32 + p * 8) * 64);
    }
    __syncthreads();                      // drains vmcnt -> LDS ready
    #pragma unroll
    for (int ks = 0; ks < 2; ++ks) {
      bf16x8 af[4], bg[4];
      #pragma unroll
      for (int i = 0; i < 4; ++i) {
        const int ra = wr * 64 + i * 16 + l16;
        af[i] = *(const bf16x8*)&As[ra * 64 + 8 * ((ks * 4 + lhi) ^ (ra & 7))];
        const int rb = wc * 64 + i * 16 + l16;
        bg[i] = *(const bf16x8*)&Bs[rb * 64 + 8 * ((ks * 4 + lhi) ^ (rb & 7))];
      }
      #pragma unroll
      for (int i = 0; i < 4; ++i)
        #pragma unroll
        for (int j = 0; j < 4; ++j)
          acc[i][j] = __builtin_amdgcn_mfma_f32_16x16x32_bf16(af[i], bg[j], acc[i][j], 0, 0, 0);
    }
  }

  // ---- epilogue: bounce C tile (128x128 bf16) through swizzled LDS ----
  // Cs elem(r, c) = r*128 + 8*((c>>3) ^ (r&15)) + (c&7)
  __syncthreads();
  ushort* Cs = lds;
  #pragma unroll
  for (int i = 0; i < 4; ++i) {
    #pragma unroll
    for (int j = 0; j < 4; ++j) {
      const int er = wr * 64 + i * 16 + lhi * 4;       // C/D: row=(lane>>4)*4+reg
      const int ec = wc * 64 + j * 16 + l16;           //      col=lane&15
      const float bv = BIAS ? bias[n0 + ec] : 0.f;
      #pragma unroll
      for (int r = 0; r < 4; ++r) {
        float val = acc[i][j][r] * scale;
        if (BIAS) val += bv;
        const int rr = er + r;
        Cs[rr * 128 + 8 * ((ec >> 3) ^ (rr & 15)) + (ec & 7)] = f2bf(val);
      }
    }
  }
  __syncthreads();
  if (EPI == 0 || EPI == 2) {
    ushort* ob = outN + (size_t)z * szO;
    #pragma unroll
    for (int p = 0; p < 8; ++p) {
      const int id = p * 256 + t, r = id >> 4, sl = id & 15;
      bf16x8 v = *(const bf16x8*)&Cs[r * 128 + 8 * (sl ^ (r & 15))];
      *(bf16x8*)(ob + (size_t)(m0 + r) * ldo + n0 + sl * 8) = v;
    }
  }
  if (EPI == 1 || EPI == 2) {
    ushort* obT = outT + (size_t)z * szOT;
    #pragma unroll
    for (int p = 0; p < 8; ++p) {
      const int id = p * 256 + t, c = id >> 4, rs = id & 15;
      bf16x8 tv;
      #pragma unroll
      for (int jj = 0; jj < 8; ++jj) {
        const int rr = rs * 8 + jj;
        tv[jj] = (short)Cs[rr * 128 + 8 * ((c >> 3) ^ (rr & 15)) + (c & 7)];
      }
      *(bf16x8*)(obT + (size_t)(n0 + c) * ldoT + m0 + rs * 8) = tv;
    }
  }
}

// ---------------------------------------------------------------------------
// In-place row softmax over a bf16 [rows][2048] matrix (one block per row):
// row <- exp(row - max(row)) / sum(exp(row - max(row)))
// ---------------------------------------------------------------------------
__global__ __launch_bounds__(256) void softmax_rows(ushort* __restrict__ attn)
{
  __shared__ float red[8];
  const int b = blockIdx.y, qi = blockIdx.x, t = threadIdx.x;
  ushort* row = attn + ((size_t)b * L_DIM + qi) * L_DIM;
  bf16x8 v = *(const bf16x8*)&row[t * 8];
  float f[8];
  #pragma unroll
  for (int j = 0; j < 8; ++j) f[j] = bf2f((ushort)v[j]);
  float m = f[0];
  #pragma unroll
  for (int j = 1; j < 8; ++j) m = fmaxf(m, f[j]);
  m = wave_red_max(m);
  if ((t & 63) == 0) red[t >> 6] = m;
  __syncthreads();
  m = fmaxf(fmaxf(red[0], red[1]), fmaxf(red[2], red[3]));
  float s = 0.f;
  #pragma unroll
  for (int j = 0; j < 8; ++j) { f[j] = __expf(f[j] - m); s += f[j]; }
  s = wave_red_sum(s);
  if ((t & 63) == 0) red[4 + (t >> 6)] = s;
  __syncthreads();
  const float inv = 1.0f / (red[4] + red[5] + red[6] + red[7]);
  bf16x8 o;
  #pragma unroll
  for (int j = 0; j < 8; ++j) o[j] = (short)f2bf(f[j] * inv);
  *(bf16x8*)&row[t * 8] = o;
}

// ---------------------------------------------------------------------------
// x [B][C][L] fp32 -> xT [B][L][C] bf16 (64x64 LDS tile transpose)
// ---------------------------------------------------------------------------
__global__ __launch_bounds__(256) void xpose(const float* __restrict__ x,
                                             ushort* __restrict__ xT)
{
  __shared__ float s[64][65];
  const int b = blockIdx.z, l0 = blockIdx.x * 64, c0 = blockIdx.y * 64;
  const int t = threadIdx.x;
  const float* xb = x + ((size_t)b * C_DIM + c0) * L_DIM + l0;
  #pragma unroll
  for (int p = 0; p < 16; ++p) {
    const int c = p * 4 + (t >> 6);
    s[c][t & 63] = xb[(size_t)c * L_DIM + (t & 63)];
  }
  __syncthreads();
  ushort* ob = xT + ((size_t)b * L_DIM + l0) * C_DIM + c0;
  #pragma unroll
  for (int p = 0; p < 16; ++p) {
    const int l = p * 4 + (t >> 6);
    ob[(size_t)l * C_DIM + (t & 63)] = f2bf(s[t & 63][l]);
  }
}

__global__ __launch_bounds__(256) void cvtw(const float* __restrict__ w,
                                            ushort* __restrict__ o)
{
  const int i = blockIdx.x * 256 + threadIdx.x;
  o[i] = f2bf(w[i]);
}

// ---------------------------------------------------------------------------
// LayerNorm over C + cross skip + transpose back to (B, C, L). vx is bf16.
// ---------------------------------------------------------------------------
__global__ __launch_bounds__(256) void ln_out(const ushort* __restrict__ vx,
    const float* __restrict__ xo, const float* __restrict__ gamma,
    const float* __restrict__ beta, float* __restrict__ out)
{
  __shared__ float s[16][513];
  __shared__ float mu[16], rsd[16];
  __shared__ float gb[512], bb[512];
  const int t = threadIdx.x;
  const int b = blockIdx.y, l0 = blockIdx.x * 16;
  #pragma unroll
  for (int r = 0; r < 2; ++r) { gb[r * 256 + t] = gamma[r * 256 + t]; bb[r * 256 + t] = beta[r * 256 + t]; }
  const ushort* vb = vx + ((size_t)b * L_DIM + l0) * C_DIM;
  #pragma unroll
  for (int p = 0; p < 4; ++p) {
    const int id = p * 256 + t;                 // 1024 chunks of 8 bf16
    const int l = id >> 6, cb = (id & 63) * 8;
    bf16x8 v = *(const bf16x8*)&vb[(size_t)l * C_DIM + cb];
    #pragma unroll
    for (int j = 0; j < 8; ++j) s[l][cb + j] = bf2f((ushort)v[j]);
  }
  __syncthreads();
  const float* xb = xo + (size_t)b * C_DIM * L_DIM + l0;
  for (int it = 0; it < 32; ++it) {
    const int idx = it * 256 + t, c = idx >> 4, l = idx & 15;
    s[l][c] += xb[(size_t)c * L_DIM + l];       // coalesced in l
  }
  __syncthreads();
  const int w = t >> 6, lane = t & 63;
  #pragma unroll
  for (int rr = 0; rr < 4; ++rr) {
    const int l = w * 4 + rr;
    float sum = 0.f, sq = 0.f;
    #pragma unroll
    for (int c0 = 0; c0 < 512; c0 += 64) {
      const float v = s[l][c0 + lane];
      sum += v; sq = fmaf(v, v, sq);
    }
    sum = wave_red_sum(sum); sq = wave_red_sum(sq);
    if (lane == 0) {
      const float m = sum * (1.f / 512.f);
      const float var = sq * (1.f / 512.f) - m * m;
      mu[l] = m; rsd[l] = rsqrtf(var + 1e-5f);
    }
  }
  __syncthreads();
  float* ob = out + (size_t)b * C_DIM * L_DIM + l0;
  for (int it = 0; it < 32; ++it) {
    const int idx = it * 256 + t, c = idx >> 4, l = idx & 15;
    const float v = (s[l][c] - mu[l]) * rsd[l] * gb[c] + bb[c];
    ob[(size_t)c * L_DIM + l] = v;              // coalesced in l
  }
}

// ---------------------------------------------------------------------------
extern "C" void kernel_launch(void* const* d_in, const int* in_sizes, int n_in,
                              void* d_out, int out_size, void* d_ws, size_t ws_size,
                              hipStream_t stream) {
  const float* x1   = (const float*)d_in[0];
  const float* x2   = (const float*)d_in[1];
  const float* w_q  = (const float*)d_in[2];
  const float* b_q  = (const float*)d_in[3];
  const float* w_k  = (const float*)d_in[4];
  const float* b_k  = (const float*)d_in[5];
  const float* w_v1 = (const float*)d_in[6];
  const float* b_v1 = (const float*)d_in[7];
  const float* w_v2 = (const float*)d_in[8];
  const float* b_v2 = (const float*)d_in[9];
  const float* gamma= (const float*)d_in[10];
  const float* beta = (const float*)d_in[11];
  float* out = (float*)d_out;

  const size_t MC  = (size_t)B_DIM * L_DIM * C_DIM;   // 8,388,608
  const size_t sQ  = (size_t)L_DIM * C_DIM;           // per-batch q/k/v stride
  const size_t sAT = (size_t)L_DIM * L_DIM;           // per-batch attn stride

  // ---- ws: exactly 128 MiB bf16 ----
  ushort* q    = (ushort*)d_ws;        // 16 MiB
  ushort* kbuf = q + MC;               // 16 MiB
  ushort* v1T  = kbuf + MC;            // 16 MiB  [C][L] per batch
  ushort* v2T  = v1T + MC;             // 16 MiB
  ushort* attn = v2T + MC;             // 64 MiB  [q][k] per batch
  // overlays in the not-yet-written attn region (dead before QK^T):
  ushort* x1T = attn;                  // 16 MiB  [B][L][C]
  ushort* x2T = attn + MC;             // 16 MiB
  ushort* wbf = attn + 2 * MC;         // 4 x 256K = 2 MiB (q|k|v1|v2)
  // PV results (bf16 [B][L][C]) in dead regions:
  ushort* vkbuf = kbuf;                // k dead after QK^T
  ushort* vqbuf = v2T;                 // v2T dead after vk GEMM
  // attnT [k][q] bf16 fills d_out (64 MiB), dead before ln writes:
  ushort* attnT = (ushort*)d_out;

  const float iscale = 0.044194173824159216f;  // 1/sqrt(512)
  const dim3 blk(256);

  // 1) weights fp32 -> bf16
  cvtw<<<1024, blk, 0, stream>>>(w_q,  wbf);
  cvtw<<<1024, blk, 0, stream>>>(w_k,  wbf + 262144);
  cvtw<<<1024, blk, 0, stream>>>(w_v1, wbf + 524288);
  cvtw<<<1024, blk, 0, stream>>>(w_v2, wbf + 786432);
  // 2) x -> xT bf16
  xpose<<<dim3(32, 8, 8), blk, 0, stream>>>(x1, x1T);
  xpose<<<dim3(32, 8, 8), blk, 0, stream>>>(x2, x2T);
  // 3) projections: q,k row-major; v1,v2 transposed ([C][L])
  gemm_mfma<0,true><<<dim3(16,4,8), blk, 0, stream>>>(x1T, wbf,          b_q,  q,    nullptr, C_DIM, C_DIM, C_DIM, C_DIM, 0,     1.0f, sQ, 0, sQ, 0);
  gemm_mfma<0,true><<<dim3(16,4,8), blk, 0, stream>>>(x2T, wbf + 262144, b_k,  kbuf, nullptr, C_DIM, C_DIM, C_DIM, C_DIM, 0,     1.0f, sQ, 0, sQ, 0);
  gemm_mfma<1,true><<<dim3(16,4,8), blk, 0, stream>>>(x1T, wbf + 524288, b_v1, nullptr, v1T,  C_DIM, C_DIM, C_DIM, 0,     L_DIM, 1.0f, sQ, 0, 0, sQ);
  gemm_mfma<1,true><<<dim3(16,4,8), blk, 0, stream>>>(x2T, wbf + 786432, b_v2, nullptr, v2T,  C_DIM, C_DIM, C_DIM, 0,     L_DIM, 1.0f, sQ, 0, 0, sQ);
  // 4) attn = q.k^T * iscale -> attn AND attnT
  gemm_mfma<2,false><<<dim3(16,16,8), blk, 0, stream>>>(q, kbuf, nullptr, attn, attnT, C_DIM, C_DIM, C_DIM, L_DIM, L_DIM, iscale, sQ, sQ, sAT, sAT);
  // 5) in-place softmax: rows of attn (over k) and rows of attnT (over q)
  softmax_rows<<<dim3(L_DIM, B_DIM), blk, 0, stream>>>(attn);
  softmax_rows<<<dim3(L_DIM, B_DIM), blk, 0, stream>>>(attnT);
  // 6) vk = P @ v2 ; vq = P^T @ v1  (plain GEMMs now)
  gemm_mfma<0,false><<<dim3(16,4,8), blk, 0, stream>>>(attn,  v2T, nullptr, vkbuf, nullptr, L_DIM, L_DIM, L_DIM, C_DIM, 0, 1.0f, sAT, sQ, sQ, 0);
  gemm_mfma<0,false><<<dim3(16,4,8), blk, 0, stream>>>(attnT, v1T, nullptr, vqbuf, nullptr, L_DIM, L_DIM, L_DIM, C_DIM, 0, 1.0f, sAT, sQ, sQ, 0);
  // 7) LN + skip + transpose back (clobbers attnT region of d_out -- now dead)
  ln_out<<<dim3(L_DIM / 16, B_DIM), blk, 0, stream>>>(vkbuf, x1, gamma, beta, out);
  ln_out<<<dim3(L_DIM / 16, B_DIM), blk, 0, stream>>>(vqbuf, x2, gamma, beta, out + MC);
}

// Round 5
// 352.417 us; speedup vs baseline: 5.6942x; 1.0543x over previous
//
#include <hip/hip_runtime.h>

#define L_DIM 2048
#define C_DIM 512
#define B_DIM 8

typedef __attribute__((ext_vector_type(8))) short bf16x8;   // 8 bf16 = 4 VGPR
typedef __attribute__((ext_vector_type(4))) float f32x4;    // MFMA acc

__device__ __forceinline__ float bf2f(ushort u) {
  union { float f; unsigned int i; } c; c.i = ((unsigned int)u) << 16; return c.f;
}
__device__ __forceinline__ ushort f2bf(float f) {
  union { float f; unsigned int i; } c; c.f = f;
  unsigned int lsb = (c.i >> 16) & 1u;
  return (ushort)((c.i + 0x7FFFu + lsb) >> 16);
}

__device__ __forceinline__ float wave_red_max(float v) {
  #pragma unroll
  for (int o = 1; o < 64; o <<= 1) v = fmaxf(v, __shfl_xor(v, o, 64));
  return v;
}
__device__ __forceinline__ float wave_red_sum(float v) {
  #pragma unroll
  for (int o = 1; o < 64; o <<= 1) v += __shfl_xor(v, o, 64);
  return v;
}

// async global->LDS, 16B per lane (dest = wave-uniform base + lane*16)
__device__ __forceinline__ void glds16(const ushort* g, ushort* l) {
  __builtin_amdgcn_global_load_lds(
      (const __attribute__((address_space(1))) void*)g,
      (__attribute__((address_space(3))) void*)l, 16, 0, 0);
}

// ---------------------------------------------------------------------------
// bf16 MFMA GEMM, D = A.B^T. Tile 128x128, BK=64, 256 thr = 4 waves (2x2).
// Double-buffered LDS (2 x 32 KiB) + prefetch-before-compute (T3 minimal):
//   stage(buf0,0); barrier;
//   loop: stage(buf^1, t+1); compute buf[cur]; barrier (drains vmcnt); swap.
// A: [m][K] bf16 (lda), B: [n][K] bf16 (ldb), staged via global_load_lds with
// pre-swizzled global source: LDS[row][slot s] holds k-chunk s^(row&7).
// EPI: 0 = row-major store, 1 = transposed store, 2 = both (bf16, LDS bounce).
// ---------------------------------------------------------------------------
template <int EPI, bool BIAS>
__global__ __launch_bounds__(256) void gemm_mfma(
    const ushort* __restrict__ A, const ushort* __restrict__ B,
    const float* __restrict__ bias,
    ushort* __restrict__ outN, ushort* __restrict__ outT,
    const int K, const int lda, const int ldb, const int ldo, const int ldoT,
    const float scale,
    const size_t szA, const size_t szB, const size_t szO, const size_t szOT)
{
  __shared__ __align__(16) ushort lds[32768];   // 64 KiB: buf b at b*16384 (As 8K | Bs 8K)

  const int t = threadIdx.x;
  const int lane = t & 63, w = t >> 6;
  const int wr = w >> 1, wc = w & 1;
  const int l16 = lane & 15, lhi = lane >> 4;
  const int m0 = blockIdx.x * 128, n0 = blockIdx.y * 128, z = blockIdx.z;

  const ushort* Ab = A + (size_t)z * szA;
  const ushort* Bb = B + (size_t)z * szB;

  f32x4 acc[4][4];
  #pragma unroll
  for (int i = 0; i < 4; ++i)
    #pragma unroll
    for (int j = 0; j < 4; ++j) { f32x4 zv = {0.f, 0.f, 0.f, 0.f}; acc[i][j] = zv; }

  // staging geometry: wave w, call p covers LDS rows w*32+p*8 .. +7;
  // lane l -> row +(l>>3), fetches global k-chunk ((l&7) ^ (row&7)) so the
  // linear LDS dest ends up swizzled: LDS[row][slot] = chunk slot^(row&7).
  const int lrow = lane >> 3;
  const int lsl  = lane & 7;

  auto stage = [&](int buf, int k0) {
    ushort* Asb = lds + buf * 16384;
    ushort* Bsb = Asb + 8192;
    #pragma unroll
    for (int p = 0; p < 4; ++p) {
      const int rbase = w * 32 + p * 8;
      const int rr = rbase + lrow;
      const int ch = lsl ^ (rr & 7);
      glds16(Ab + (size_t)(m0 + rr) * lda + k0 + ch * 8, Asb + rbase * 64);
      glds16(Bb + (size_t)(n0 + rr) * ldb + k0 + ch * 8, Bsb + rbase * 64);
    }
  };

  const int KT = K >> 6;
  stage(0, 0);
  __syncthreads();                          // drains vmcnt(0) -> buf0 ready
  int cur = 0;
  for (int kt = 0; kt < KT; ++kt) {
    if (kt + 1 < KT) stage(cur ^ 1, (kt + 1) << 6);   // fly during compute
    const ushort* Asb = lds + cur * 16384;
    const ushort* Bsb = Asb + 8192;
    #pragma unroll
    for (int ks = 0; ks < 2; ++ks) {
      bf16x8 af[4], bg[4];
      #pragma unroll
      for (int i = 0; i < 4; ++i) {
        const int ra = wr * 64 + i * 16 + l16;
        af[i] = *(const bf16x8*)&Asb[ra * 64 + 8 * ((ks * 4 + lhi) ^ (ra & 7))];
        const int rb = wc * 64 + i * 16 + l16;
        bg[i] = *(const bf16x8*)&Bsb[rb * 64 + 8 * ((ks * 4 + lhi) ^ (rb & 7))];
      }
      #pragma unroll
      for (int i = 0; i < 4; ++i)
        #pragma unroll
        for (int j = 0; j < 4; ++j)
          acc[i][j] = __builtin_amdgcn_mfma_f32_16x16x32_bf16(af[i], bg[j], acc[i][j], 0, 0, 0);
    }
    __syncthreads();     // all waves done with buf[cur]; prefetch landed
    cur ^= 1;
  }

  // ---- epilogue: bounce C tile (128x128 bf16) through swizzled LDS ----
  // Cs elem(r, c) = r*128 + 8*((c>>3) ^ (r&15)) + (c&7)
  ushort* Cs = lds;
  #pragma unroll
  for (int i = 0; i < 4; ++i) {
    #pragma unroll
    for (int j = 0; j < 4; ++j) {
      const int er = wr * 64 + i * 16 + lhi * 4;       // C/D: row=(lane>>4)*4+reg
      const int ec = wc * 64 + j * 16 + l16;           //      col=lane&15
      const float bv = BIAS ? bias[n0 + ec] : 0.f;
      #pragma unroll
      for (int r = 0; r < 4; ++r) {
        float val = acc[i][j][r] * scale;
        if (BIAS) val += bv;
        const int rr = er + r;
        Cs[rr * 128 + 8 * ((ec >> 3) ^ (rr & 15)) + (ec & 7)] = f2bf(val);
      }
    }
  }
  __syncthreads();
  if (EPI == 0 || EPI == 2) {
    ushort* ob = outN + (size_t)z * szO;
    #pragma unroll
    for (int p = 0; p < 8; ++p) {
      const int id = p * 256 + t, r = id >> 4, sl = id & 15;
      bf16x8 v = *(const bf16x8*)&Cs[r * 128 + 8 * (sl ^ (r & 15))];
      *(bf16x8*)(ob + (size_t)(m0 + r) * ldo + n0 + sl * 8) = v;
    }
  }
  if (EPI == 1 || EPI == 2) {
    ushort* obT = outT + (size_t)z * szOT;
    #pragma unroll
    for (int p = 0; p < 8; ++p) {
      const int id = p * 256 + t, c = id >> 4, rs = id & 15;
      bf16x8 tv;
      #pragma unroll
      for (int jj = 0; jj < 8; ++jj) {
        const int rr = rs * 8 + jj;
        tv[jj] = (short)Cs[rr * 128 + 8 * ((c >> 3) ^ (rr & 15)) + (c & 7)];
      }
      *(bf16x8*)(obT + (size_t)(n0 + c) * ldoT + m0 + rs * 8) = tv;
    }
  }
}

// ---------------------------------------------------------------------------
// In-place row softmax over a bf16 [rows][2048] matrix (one block per row):
// row <- exp(row - max(row)) / sum(exp(row - max(row)))
// ---------------------------------------------------------------------------
__global__ __launch_bounds__(256) void softmax_rows(ushort* __restrict__ attn)
{
  __shared__ float red[8];
  const int b = blockIdx.y, qi = blockIdx.x, t = threadIdx.x;
  ushort* row = attn + ((size_t)b * L_DIM + qi) * L_DIM;
  bf16x8 v = *(const bf16x8*)&row[t * 8];
  float f[8];
  #pragma unroll
  for (int j = 0; j < 8; ++j) f[j] = bf2f((ushort)v[j]);
  float m = f[0];
  #pragma unroll
  for (int j = 1; j < 8; ++j) m = fmaxf(m, f[j]);
  m = wave_red_max(m);
  if ((t & 63) == 0) red[t >> 6] = m;
  __syncthreads();
  m = fmaxf(fmaxf(red[0], red[1]), fmaxf(red[2], red[3]));
  float s = 0.f;
  #pragma unroll
  for (int j = 0; j < 8; ++j) { f[j] = __expf(f[j] - m); s += f[j]; }
  s = wave_red_sum(s);
  if ((t & 63) == 0) red[4 + (t >> 6)] = s;
  __syncthreads();
  const float inv = 1.0f / (red[4] + red[5] + red[6] + red[7]);
  bf16x8 o;
  #pragma unroll
  for (int j = 0; j < 8; ++j) o[j] = (short)f2bf(f[j] * inv);
  *(bf16x8*)&row[t * 8] = o;
}

// ---------------------------------------------------------------------------
// x [B][C][L] fp32 -> xT [B][L][C] bf16 (64x64 LDS tile transpose)
// ---------------------------------------------------------------------------
__global__ __launch_bounds__(256) void xpose(const float* __restrict__ x,
                                             ushort* __restrict__ xT)
{
  __shared__ float s[64][65];
  const int b = blockIdx.z, l0 = blockIdx.x * 64, c0 = blockIdx.y * 64;
  const int t = threadIdx.x;
  const float* xb = x + ((size_t)b * C_DIM + c0) * L_DIM + l0;
  #pragma unroll
  for (int p = 0; p < 16; ++p) {
    const int c = p * 4 + (t >> 6);
    s[c][t & 63] = xb[(size_t)c * L_DIM + (t & 63)];
  }
  __syncthreads();
  ushort* ob = xT + ((size_t)b * L_DIM + l0) * C_DIM + c0;
  #pragma unroll
  for (int p = 0; p < 16; ++p) {
    const int l = p * 4 + (t >> 6);
    ob[(size_t)l * C_DIM + (t & 63)] = f2bf(s[t & 63][l]);
  }
}

__global__ __launch_bounds__(256) void cvtw(const float* __restrict__ w,
                                            ushort* __restrict__ o)
{
  const int i = blockIdx.x * 256 + threadIdx.x;
  o[i] = f2bf(w[i]);
}

// ---------------------------------------------------------------------------
// LayerNorm over C + cross skip + transpose back to (B, C, L). vx is bf16.
// ---------------------------------------------------------------------------
__global__ __launch_bounds__(256) void ln_out(const ushort* __restrict__ vx,
    const float* __restrict__ xo, const float* __restrict__ gamma,
    const float* __restrict__ beta, float* __restrict__ out)
{
  __shared__ float s[16][513];
  __shared__ float mu[16], rsd[16];
  __shared__ float gb[512], bb[512];
  const int t = threadIdx.x;
  const int b = blockIdx.y, l0 = blockIdx.x * 16;
  #pragma unroll
  for (int r = 0; r < 2; ++r) { gb[r * 256 + t] = gamma[r * 256 + t]; bb[r * 256 + t] = beta[r * 256 + t]; }
  const ushort* vb = vx + ((size_t)b * L_DIM + l0) * C_DIM;
  #pragma unroll
  for (int p = 0; p < 4; ++p) {
    const int id = p * 256 + t;                 // 1024 chunks of 8 bf16
    const int l = id >> 6, cb = (id & 63) * 8;
    bf16x8 v = *(const bf16x8*)&vb[(size_t)l * C_DIM + cb];
    #pragma unroll
    for (int j = 0; j < 8; ++j) s[l][cb + j] = bf2f((ushort)v[j]);
  }
  __syncthreads();
  const float* xb = xo + (size_t)b * C_DIM * L_DIM + l0;
  for (int it = 0; it < 32; ++it) {
    const int idx = it * 256 + t, c = idx >> 4, l = idx & 15;
    s[l][c] += xb[(size_t)c * L_DIM + l];       // coalesced in l
  }
  __syncthreads();
  const int w = t >> 6, lane = t & 63;
  #pragma unroll
  for (int rr = 0; rr < 4; ++rr) {
    const int l = w * 4 + rr;
    float sum = 0.f, sq = 0.f;
    #pragma unroll
    for (int c0 = 0; c0 < 512; c0 += 64) {
      const float v = s[l][c0 + lane];
      sum += v; sq = fmaf(v, v, sq);
    }
    sum = wave_red_sum(sum); sq = wave_red_sum(sq);
    if (lane == 0) {
      const float m = sum * (1.f / 512.f);
      const float var = sq * (1.f / 512.f) - m * m;
      mu[l] = m; rsd[l] = rsqrtf(var + 1e-5f);
    }
  }
  __syncthreads();
  float* ob = out + (size_t)b * C_DIM * L_DIM + l0;
  for (int it = 0; it < 32; ++it) {
    const int idx = it * 256 + t, c = idx >> 4, l = idx & 15;
    const float v = (s[l][c] - mu[l]) * rsd[l] * gb[c] + bb[c];
    ob[(size_t)c * L_DIM + l] = v;              // coalesced in l
  }
}

// ---------------------------------------------------------------------------
extern "C" void kernel_launch(void* const* d_in, const int* in_sizes, int n_in,
                              void* d_out, int out_size, void* d_ws, size_t ws_size,
                              hipStream_t stream) {
  const float* x1   = (const float*)d_in[0];
  const float* x2   = (const float*)d_in[1];
  const float* w_q  = (const float*)d_in[2];
  const float* b_q  = (const float*)d_in[3];
  const float* w_k  = (const float*)d_in[4];
  const float* b_k  = (const float*)d_in[5];
  const float* w_v1 = (const float*)d_in[6];
  const float* b_v1 = (const float*)d_in[7];
  const float* w_v2 = (const float*)d_in[8];
  const float* b_v2 = (const float*)d_in[9];
  const float* gamma= (const float*)d_in[10];
  const float* beta = (const float*)d_in[11];
  float* out = (float*)d_out;

  const size_t MC  = (size_t)B_DIM * L_DIM * C_DIM;   // 8,388,608
  const size_t sQ  = (size_t)L_DIM * C_DIM;           // per-batch q/k/v stride
  const size_t sAT = (size_t)L_DIM * L_DIM;           // per-batch attn stride

  // ---- ws: exactly 128 MiB bf16 ----
  ushort* q    = (ushort*)d_ws;        // 16 MiB
  ushort* kbuf = q + MC;               // 16 MiB
  ushort* v1T  = kbuf + MC;            // 16 MiB  [C][L] per batch
  ushort* v2T  = v1T + MC;             // 16 MiB
  ushort* attn = v2T + MC;             // 64 MiB  [q][k] per batch
  // overlays in the not-yet-written attn region (dead before QK^T):
  ushort* x1T = attn;                  // 16 MiB  [B][L][C]
  ushort* x2T = attn + MC;             // 16 MiB
  ushort* wbf = attn + 2 * MC;         // 4 x 256K = 2 MiB (q|k|v1|v2)
  // PV results (bf16 [B][L][C]) in dead regions:
  ushort* vkbuf = kbuf;                // k dead after QK^T
  ushort* vqbuf = v2T;                 // v2T dead after vk GEMM
  // attnT [k][q] bf16 fills d_out (64 MiB), dead before ln writes:
  ushort* attnT = (ushort*)d_out;

  const float iscale = 0.044194173824159216f;  // 1/sqrt(512)
  const dim3 blk(256);

  // 1) weights fp32 -> bf16
  cvtw<<<1024, blk, 0, stream>>>(w_q,  wbf);
  cvtw<<<1024, blk, 0, stream>>>(w_k,  wbf + 262144);
  cvtw<<<1024, blk, 0, stream>>>(w_v1, wbf + 524288);
  cvtw<<<1024, blk, 0, stream>>>(w_v2, wbf + 786432);
  // 2) x -> xT bf16
  xpose<<<dim3(32, 8, 8), blk, 0, stream>>>(x1, x1T);
  xpose<<<dim3(32, 8, 8), blk, 0, stream>>>(x2, x2T);
  // 3) projections: q,k row-major; v1,v2 transposed ([C][L])
  gemm_mfma<0,true><<<dim3(16,4,8), blk, 0, stream>>>(x1T, wbf,          b_q,  q,    nullptr, C_DIM, C_DIM, C_DIM, C_DIM, 0,     1.0f, sQ, 0, sQ, 0);
  gemm_mfma<0,true><<<dim3(16,4,8), blk, 0, stream>>>(x2T, wbf + 262144, b_k,  kbuf, nullptr, C_DIM, C_DIM, C_DIM, C_DIM, 0,     1.0f, sQ, 0, sQ, 0);
  gemm_mfma<1,true><<<dim3(16,4,8), blk, 0, stream>>>(x1T, wbf + 524288, b_v1, nullptr, v1T,  C_DIM, C_DIM, C_DIM, 0,     L_DIM, 1.0f, sQ, 0, 0, sQ);
  gemm_mfma<1,true><<<dim3(16,4,8), blk, 0, stream>>>(x2T, wbf + 786432, b_v2, nullptr, v2T,  C_DIM, C_DIM, C_DIM, 0,     L_DIM, 1.0f, sQ, 0, 0, sQ);
  // 4) attn = q.k^T * iscale -> attn AND attnT
  gemm_mfma<2,false><<<dim3(16,16,8), blk, 0, stream>>>(q, kbuf, nullptr, attn, attnT, C_DIM, C_DIM, C_DIM, L_DIM, L_DIM, iscale, sQ, sQ, sAT, sAT);
  // 5) in-place softmax: rows of attn (over k) and rows of attnT (over q)
  softmax_rows<<<dim3(L_DIM, B_DIM), blk, 0, stream>>>(attn);
  softmax_rows<<<dim3(L_DIM, B_DIM), blk, 0, stream>>>(attnT);
  // 6) vk = P @ v2 ; vq = P^T @ v1  (plain GEMMs now)
  gemm_mfma<0,false><<<dim3(16,4,8), blk, 0, stream>>>(attn,  v2T, nullptr, vkbuf, nullptr, L_DIM, L_DIM, L_DIM, C_DIM, 0, 1.0f, sAT, sQ, sQ, 0);
  gemm_mfma<0,false><<<dim3(16,4,8), blk, 0, stream>>>(attnT, v1T, nullptr, vqbuf, nullptr, L_DIM, L_DIM, L_DIM, C_DIM, 0, 1.0f, sAT, sQ, sQ, 0);
  // 7) LN + skip + transpose back (clobbers attnT region of d_out -- now dead)
  ln_out<<<dim3(L_DIM / 16, B_DIM), blk, 0, stream>>>(vkbuf, x1, gamma, beta, out);
  ln_out<<<dim3(L_DIM / 16, B_DIM), blk, 0, stream>>>(vqbuf, x2, gamma, beta, out + MC);
}